// Round 1
// baseline (159591.150 us; speedup 1.0000x reference)
//
#include <hip/hip_runtime.h>
#include <hip/hip_fp16.h>

// MC-LSTM persistent-recurrence kernel for MI355X.
// T=2048 sequential steps; 97 GEMM WGs (one per 64-col row-unit of W, weights
// register/LDS resident) + 128 combine WGs; device-scope atomic flag syncs.

#define TT 2048
#define BB 128
#define HH 64
#define GG 128
#define NGEMM 97       // 32 i-rows + 64 r-rows + 1 o-row
#define NCOMB 128
#define NWG (NGEMM + NCOMB)

typedef _Float16 f16x8 __attribute__((ext_vector_type(8)));
typedef float f32x4 __attribute__((ext_vector_type(4)));

#define LD_RLX(p)   __hip_atomic_load((p), __ATOMIC_RELAXED, __HIP_MEMORY_SCOPE_AGENT)
#define LD_ACQ(p)   __hip_atomic_load((p), __ATOMIC_ACQUIRE, __HIP_MEMORY_SCOPE_AGENT)
#define ST_RLX(p,v) __hip_atomic_store((p), (v), __ATOMIC_RELAXED, __HIP_MEMORY_SCOPE_AGENT)

// ---- ws layout (bytes) ----
#define OFF_WH    0u
#define SZ_WH     (NGEMM * 64 * 128 * 2)            // 1,589,248  fp16
#define OFF_SLAB  (SZ_WH)                           // 96 rows x 8192 fp32
#define SZ_SLAB   (96 * 8192 * 4)                   // 3,145,728
#define OFF_OBUF  (OFF_SLAB + SZ_SLAB)
#define SZ_OBUF   (8192 * 4)
#define OFF_CBUF  (OFF_OBUF + SZ_OBUF)
#define SZ_CBUF   (8192 * 4)
#define OFF_NORM  (OFF_CBUF + SZ_CBUF)
#define SZ_NORM   ((TT + 1) * 4)
#define OFF_CTRA  (OFF_NORM + SZ_NORM)
#define OFF_CTRB  (OFF_CTRA + SZ_NORM)
#define ZERO_OFF  OFF_CBUF
#define ZERO_LEN  (SZ_CBUF + 3 * SZ_NORM)

// Repack W into [row][h][g] fp16 (B^T layout for MFMA B-operand).
__global__ void prep_kernel(const float* __restrict__ Wi, const float* __restrict__ Wr,
                            const float* __restrict__ Wo, _Float16* __restrict__ Wh) {
  int idx = blockIdx.x * 256 + threadIdx.x;
  if (idx >= NGEMM * 64 * 128) return;
  int g = idx & 127, h = (idx >> 7) & 63, r = idx >> 13;
  float v;
  if (r < 32)      v = Wi[g * 2048 + r * 64 + h];
  else if (r < 96) v = Wr[g * 4096 + (r - 32) * 64 + h];
  else             v = Wo[g * 64 + h];
  Wh[idx] = (_Float16)v;
}

__launch_bounds__(256, 1)
__global__ void mclstm_kernel(const float* __restrict__ xm, const float* __restrict__ xa,
                              const float* __restrict__ bi, const float* __restrict__ br,
                              const float* __restrict__ bo,
                              const _Float16* __restrict__ Wh,
                              float* __restrict__ slab, float* __restrict__ obuf,
                              float* __restrict__ cbuf, float* __restrict__ normAcc,
                              unsigned* __restrict__ ctrA, unsigned* __restrict__ ctrB,
                              float* __restrict__ out) {
  const int w = blockIdx.x, tid = threadIdx.x;

  if (w < NGEMM) {
    // ---------------- GEMM role: one 64-col row-unit, all 128 batches ----------------
    __shared__ __align__(16) _Float16 featL[128][136];  // [b][g], 272 B rows (pad: bank-stride 4)
    __shared__ __align__(16) _Float16 WL[64][136];      // [h][g]  (B^T)
    __shared__ float wrow[128];                         // einsum weight per b (xm or raw c)
    __shared__ float brow[64];                          // bias for this row-unit
    __shared__ float bc;                                // norm broadcast

    for (int i = tid; i < 64 * 128; i += 256) WL[i >> 7][i & 127] = Wh[w * 8192 + i];
    if (tid < 64)
      brow[tid] = (w < 32) ? bi[w * 64 + tid]
                : (w < 96) ? br[(w - 32) * 64 + tid] : bo[tid];
    __syncthreads();

    const int wv = tid >> 6, l = tid & 63, lr = l & 15, lk = l >> 4;

    // B-fragments are constant over t: hoist into registers once.
    f16x8 Bf[4][4];
#pragma unroll
    for (int ht = 0; ht < 4; ++ht)
#pragma unroll
      for (int kk = 0; kk < 4; ++kk)
        Bf[ht][kk] = *(const f16x8*)&WL[ht * 16 + lr][kk * 32 + lk * 8];

    for (int t = 0; t < TT; ++t) {
      // Prefetch input-only x into feat BEFORE waiting on the recurrence.
      const float* xmt = xm + (size_t)t * (BB * 32);
#pragma unroll 4
      for (int i = tid; i < 4096; i += 256) {
        int b = i >> 5, m = i & 31;
        float v = xmt[i];
        featL[b][m] = (_Float16)v;
        if (w < 32 && m == w) wrow[b] = v;  // fp32 weight for i-einsum
      }
      const float* xat = xa + (size_t)t * (BB * 32);
#pragma unroll 4
      for (int i = tid; i < 4096; i += 256)
        featL[i >> 5][32 + (i & 31)] = (_Float16)xat[i];

      if (t > 0) {
        if (tid == 0)
          while (LD_ACQ(&ctrA[t]) < (unsigned)NCOMB) __builtin_amdgcn_s_sleep(1);
        __syncthreads();
        __threadfence();
      }
      if (tid == 0) bc = LD_RLX(&normAcc[t]);
      __syncthreads();
      const float inv = 1.0f / (bc + 1e-5f);

      // c -> cn into feat (batched loads so relaxed atomics pipeline).
      float cv[32];
#pragma unroll
      for (int k = 0; k < 32; ++k) cv[k] = LD_RLX(&cbuf[tid + k * 256]);
#pragma unroll
      for (int k = 0; k < 32; ++k) {
        int i = tid + k * 256;
        int b = i >> 6, h = i & 63;
        featL[b][64 + h] = (_Float16)(cv[k] * inv);
        if (w >= 32 && w < 96 && h == w - 32) wrow[b] = cv[k];  // raw c for r-einsum
      }
      __syncthreads();

      // MFMA: [128 x 128] @ [128 x 64]; wave wv owns b-tiles {2wv, 2wv+1}
      f32x4 acc[2][4];
#pragma unroll
      for (int a2 = 0; a2 < 2; ++a2)
#pragma unroll
        for (int h2 = 0; h2 < 4; ++h2) acc[a2][h2] = (f32x4){0.f, 0.f, 0.f, 0.f};
#pragma unroll
      for (int bt2 = 0; bt2 < 2; ++bt2) {
        f16x8 Af[4];
#pragma unroll
        for (int kk = 0; kk < 4; ++kk)
          Af[kk] = *(const f16x8*)&featL[(wv * 2 + bt2) * 16 + lr][kk * 32 + lk * 8];
#pragma unroll
        for (int ht = 0; ht < 4; ++ht)
#pragma unroll
          for (int kk = 0; kk < 4; ++kk)
            acc[bt2][ht] = __builtin_amdgcn_mfma_f32_16x16x32_f16(Af[kk], Bf[ht][kk],
                                                                  acc[bt2][ht], 0, 0, 0);
      }

      // Epilogue. D layout: col(h-part)=l&15, row(b-part)=(l>>4)*4+reg.
      if (w == 96) {  // o-row: sigmoid only
#pragma unroll
        for (int bt2 = 0; bt2 < 2; ++bt2)
#pragma unroll
          for (int ht = 0; ht < 4; ++ht)
#pragma unroll
            for (int rr = 0; rr < 4; ++rr) {
              float z = acc[bt2][ht][rr] + brow[ht * 16 + lr];
              float s = 1.0f / (1.0f + __expf(-z));
              int b = (wv * 2 + bt2) * 16 + lk * 4 + rr;
              ST_RLX(&obuf[b * 64 + ht * 16 + lr], s);
            }
      } else {  // i/r rows: sigmoid, L1-norm over h, scale by weight, write slab
        float sv[2][4][4];
        float rs[2][4];
#pragma unroll
        for (int bt2 = 0; bt2 < 2; ++bt2)
#pragma unroll
          for (int rr = 0; rr < 4; ++rr) {
            float sum = 0.f;
#pragma unroll
            for (int ht = 0; ht < 4; ++ht) {
              float z = acc[bt2][ht][rr] + brow[ht * 16 + lr];
              float s = 1.0f / (1.0f + __expf(-z));
              sv[bt2][ht][rr] = s;
              sum += s;
            }
            rs[bt2][rr] = sum;
          }
#pragma unroll
        for (int bt2 = 0; bt2 < 2; ++bt2)
#pragma unroll
          for (int rr = 0; rr < 4; ++rr) {
            float r4 = rs[bt2][rr];
            r4 += __shfl_xor(r4, 1, 64);
            r4 += __shfl_xor(r4, 2, 64);
            r4 += __shfl_xor(r4, 4, 64);
            r4 += __shfl_xor(r4, 8, 64);  // rowsum over all 64 h
            int b = (wv * 2 + bt2) * 16 + lk * 4 + rr;
            float sc = wrow[b] / fmaxf(r4, 1e-12f);
#pragma unroll
            for (int ht = 0; ht < 4; ++ht)
              ST_RLX(&slab[w * 8192 + b * 64 + ht * 16 + lr], sv[bt2][ht][rr] * sc);
          }
      }
      __threadfence();
      __syncthreads();
      if (tid == 0)
        __hip_atomic_fetch_add(&ctrB[t], 1u, __ATOMIC_RELEASE, __HIP_MEMORY_SCOPE_AGENT);
    }
  } else {
    // ---------------- combine role: 64 (b,h) outputs per WG ----------------
    const int cw = w - NGEMM;
    const int lane = tid & 63, rp = tid >> 6;
    const int bh = cw * 64 + lane;
    __shared__ float red[4][64];

    for (int t = 0; t < TT; ++t) {
      if (tid == 0)
        while (LD_ACQ(&ctrB[t]) < (unsigned)NGEMM) __builtin_amdgcn_s_sleep(1);
      __syncthreads();
      __threadfence();

      float v[24];
#pragma unroll
      for (int j = 0; j < 24; ++j) v[j] = LD_RLX(&slab[(rp * 24 + j) * 8192 + bh]);
      float s = 0.f;
#pragma unroll
      for (int j = 0; j < 24; ++j) s += v[j];
      red[rp][lane] = s;
      float o = (rp == 0) ? LD_RLX(&obuf[bh]) : 0.f;
      __syncthreads();

      if (rp == 0) {
        float mn = red[0][lane] + red[1][lane] + red[2][lane] + red[3][lane];
        float mo = o * mn;
        float cn = (1.0f - o) * mn;
        out[(size_t)t * 8192 + bh] = mo;
        out[(size_t)(TT + t) * 8192 + bh] = cn;
        ST_RLX(&cbuf[bh], cn);
        float ns = fabsf(cn);
        ns += __shfl_xor(ns, 1, 64);
        ns += __shfl_xor(ns, 2, 64);
        ns += __shfl_xor(ns, 4, 64);
        ns += __shfl_xor(ns, 8, 64);
        ns += __shfl_xor(ns, 16, 64);
        ns += __shfl_xor(ns, 32, 64);
        if (lane == 0)
          __hip_atomic_fetch_add(&normAcc[t + 1], ns, __ATOMIC_RELAXED,
                                 __HIP_MEMORY_SCOPE_AGENT);
      }
      __threadfence();
      __syncthreads();
      if (tid == 0)
        __hip_atomic_fetch_add(&ctrA[t + 1], 1u, __ATOMIC_RELEASE, __HIP_MEMORY_SCOPE_AGENT);
    }
  }
}

extern "C" void kernel_launch(void* const* d_in, const int* in_sizes, int n_in,
                              void* d_out, int out_size, void* d_ws, size_t ws_size,
                              hipStream_t stream) {
  (void)in_sizes; (void)n_in; (void)out_size; (void)ws_size;
  const float* xm = (const float*)d_in[0];
  const float* xa = (const float*)d_in[1];
  const float* Wi = (const float*)d_in[2];
  const float* bi = (const float*)d_in[3];
  const float* Wr = (const float*)d_in[4];
  const float* br = (const float*)d_in[5];
  const float* Wo = (const float*)d_in[6];
  const float* bo = (const float*)d_in[7];

  char* ws = (char*)d_ws;
  _Float16* Wh    = (_Float16*)(ws + OFF_WH);
  float* slab     = (float*)(ws + OFF_SLAB);
  float* obuf     = (float*)(ws + OFF_OBUF);
  float* cbuf     = (float*)(ws + OFF_CBUF);
  float* normAcc  = (float*)(ws + OFF_NORM);
  unsigned* ctrA  = (unsigned*)(ws + OFF_CTRA);
  unsigned* ctrB  = (unsigned*)(ws + OFF_CTRB);

  // Zero recurrence state + counters every call (graph replays reuse ws).
  hipMemsetAsync(ws + ZERO_OFF, 0, ZERO_LEN, stream);
  prep_kernel<<<(NGEMM * 64 * 128 + 255) / 256, 256, 0, stream>>>(Wi, Wr, Wo, Wh);
  mclstm_kernel<<<NWG, 256, 0, stream>>>(xm, xa, bi, br, bo, Wh, slab, obuf, cbuf,
                                         normAcc, ctrA, ctrB, (float*)d_out);
}

// Round 2
// 36444.958 us; speedup vs baseline: 4.3790x; 4.3790x over previous
//
#include <hip/hip_runtime.h>
#include <hip/hip_fp16.h>

// MC-LSTM persistent recurrence, v2: 48 WGs, batch-split waves, ONE barrier/step.
// Each WG: 2 row-units (i/r) + redundant o; m_new via global f32 atomicAdd;
// c state wave-private in LDS; scalar L1 norm computed redundantly (bit-identical).

#define TT 2048
#define NWG 48
#define UPW 2

typedef _Float16 f16;
typedef _Float16 f16x8 __attribute__((ext_vector_type(8)));
typedef _Float16 f16x4 __attribute__((ext_vector_type(4)));
typedef float f32x4 __attribute__((ext_vector_type(4)));
typedef float f32x2 __attribute__((ext_vector_type(2)));

#define LD_RLX(p)   __hip_atomic_load((p), __ATOMIC_RELAXED, __HIP_MEMORY_SCOPE_AGENT)
#define ST_RLX(p,v) __hip_atomic_store((p), (v), __ATOMIC_RELAXED, __HIP_MEMORY_SCOPE_AGENT)

// ---- ws layout (bytes) ----
#define OFF_WH    0u
#define SZ_WH     (97u * 8192u * 2u)                 // fp16 weights [unit][h][g]
#define OFF_ACC   ((OFF_WH + SZ_WH + 255u) & ~255u)  // 3 x [128][64] f32 m_new accum
#define SZ_ACC    (3u * 8192u * 4u)
#define OFF_OB    (OFF_ACC + SZ_ACC)                 // 2 x [128][64] f32 o gate
#define SZ_OB     (2u * 8192u * 4u)
#define OFF_CTR   (OFF_OB + SZ_OB)                   // per-step barrier counters
#define SZ_CTR    (TT * 4u)
#define ZERO_OFF  OFF_ACC
#define ZERO_LEN  (SZ_ACC + SZ_OB + SZ_CTR)

__global__ void prep_kernel(const float* __restrict__ Wi, const float* __restrict__ Wr,
                            const float* __restrict__ Wo, f16* __restrict__ Wh) {
  int idx = blockIdx.x * 256 + threadIdx.x;
  if (idx >= 97 * 8192) return;
  int g = idx & 127, h = (idx >> 7) & 63, r = idx >> 13;
  float v;
  if (r < 32)      v = Wi[g * 2048 + r * 64 + h];
  else if (r < 96) v = Wr[g * 4096 + (r - 32) * 64 + h];
  else             v = Wo[g * 64 + h];
  Wh[idx] = (f16)v;
}

__launch_bounds__(256, 1)
__global__ void mclstm_kernel(const float* __restrict__ xm, const float* __restrict__ xa,
                              const float* __restrict__ bi, const float* __restrict__ br,
                              const float* __restrict__ bo, const f16* __restrict__ Wh,
                              float* __restrict__ accg, float* __restrict__ obuf,
                              unsigned* __restrict__ ctr, float* __restrict__ out) {
  const int j = blockIdx.x, tid = threadIdx.x;
  const int w = tid >> 6, l = tid & 63, lr = l & 15, lk = l >> 4;

  __shared__ __align__(16) f16 featX[128][72];   // cols 0..31 xm, 32..63 xa (wave-private rows)
  __shared__ float cL[128][66];                  // raw c state, f32 (wave-private rows)
  __shared__ float nred[4];

  for (int e = tid; e < 128 * 66; e += 256) ((float*)cL)[e] = 0.f;

  // ---- persistent B fragments (weights live in registers for the whole run) ----
  f16x8 Bf[UPW][4][4], Bo_[4][4];
  float bu[UPW][4], boR[4];
#pragma unroll
  for (int un = 0; un < UPW; ++un) {
    int u = j * UPW + un;
#pragma unroll
    for (int ht = 0; ht < 4; ++ht) {
      int col = ht * 16 + lr;
      bu[un][ht] = (u < 32) ? bi[u * 64 + col] : br[(u - 32) * 64 + col];
#pragma unroll
      for (int kk = 0; kk < 4; ++kk)
        Bf[un][ht][kk] = *(const f16x8*)(Wh + u * 8192 + col * 128 + kk * 32 + lk * 8);
    }
  }
#pragma unroll
  for (int ht = 0; ht < 4; ++ht) {
    int col = ht * 16 + lr;
    boR[ht] = bo[col];
#pragma unroll
    for (int kk = 0; kk < 4; ++kk)
      Bo_[ht][kk] = *(const f16x8*)(Wh + 96 * 8192 + col * 128 + kk * 32 + lk * 8);
  }
  __syncthreads();

  float inv = 0.0f;  // t=0: c==0 so cn==0 regardless
  // prefetch x for t=0 (wave-private quads, coalesced)
  float4 xmr[4], xar[4];
  {
    const float4* x4 = (const float4*)xm;
    const float4* a4 = (const float4*)xa;
#pragma unroll
    for (int k = 0; k < 4; ++k) {
      int idx4 = w * 256 + k * 64 + l;
      xmr[k] = x4[idx4];
      xar[k] = a4[idx4];
    }
  }

  for (int t = 0; t < TT; ++t) {
    // ---- feat build (wave-private; no syncthreads needed) ----
#pragma unroll
    for (int k = 0; k < 4; ++k) {
      int idx4 = w * 256 + k * 64 + l;
      int row = idx4 >> 3, cq = (idx4 & 7) * 4;
      float4 v = xmr[k];
      f16x4 hm = {(f16)v.x, (f16)v.y, (f16)v.z, (f16)v.w};
      *(f16x4*)&featX[row][cq] = hm;
      float4 va = xar[k];
      f16x4 ha = {(f16)va.x, (f16)va.y, (f16)va.z, (f16)va.w};
      *(f16x4*)&featX[row][32 + cq] = ha;
    }

    // ---- GEMM: [32b x 128g] @ [128g x 192cols] per wave ----
    f32x4 acc[UPW][2][4];
    f32x4 aco[2][4];
#pragma unroll
    for (int un = 0; un < UPW; ++un)
#pragma unroll
      for (int bt = 0; bt < 2; ++bt)
#pragma unroll
        for (int ht = 0; ht < 4; ++ht) acc[un][bt][ht] = (f32x4){0.f, 0.f, 0.f, 0.f};
#pragma unroll
    for (int bt = 0; bt < 2; ++bt)
#pragma unroll
      for (int ht = 0; ht < 4; ++ht) aco[bt][ht] = (f32x4){0.f, 0.f, 0.f, 0.f};

#pragma unroll
    for (int bt = 0; bt < 2; ++bt) {
      int row = (2 * w + bt) * 16 + lr;
      f16x8 Af[4];
      Af[0] = *(const f16x8*)&featX[row][lk * 8];
      Af[1] = *(const f16x8*)&featX[row][32 + lk * 8];
#pragma unroll
      for (int kk = 2; kk < 4; ++kk) {
        int h0 = (kk - 2) * 32 + lk * 8;
        f16x8 af;
#pragma unroll
        for (int i2 = 0; i2 < 4; ++i2) {
          f32x2 c2 = *(const f32x2*)&cL[row][h0 + i2 * 2];
          af[i2 * 2]     = (f16)(c2.x * inv);
          af[i2 * 2 + 1] = (f16)(c2.y * inv);
        }
        Af[kk] = af;
      }
#pragma unroll
      for (int un = 0; un < UPW; ++un)
#pragma unroll
        for (int ht = 0; ht < 4; ++ht)
#pragma unroll
          for (int kk = 0; kk < 4; ++kk)
            acc[un][bt][ht] = __builtin_amdgcn_mfma_f32_16x16x32_f16(
                Af[kk], Bf[un][ht][kk], acc[un][bt][ht], 0, 0, 0);
#pragma unroll
      for (int ht = 0; ht < 4; ++ht)
#pragma unroll
        for (int kk = 0; kk < 4; ++kk)
          aco[bt][ht] = __builtin_amdgcn_mfma_f32_16x16x32_f16(
              Af[kk], Bo_[ht][kk], aco[bt][ht], 0, 0, 0);
    }

    // ---- epilogue: sigmoid, L1-norm over h, scale, accumulate contribution ----
    float contrib[2][4][4];
#pragma unroll
    for (int bt = 0; bt < 2; ++bt)
#pragma unroll
      for (int ht = 0; ht < 4; ++ht)
#pragma unroll
        for (int rr = 0; rr < 4; ++rr) contrib[bt][ht][rr] = 0.f;

    const float* xmtp = xm + (size_t)t * 4096;
#pragma unroll
    for (int un = 0; un < UPW; ++un) {
      int u = j * UPW + un;
      bool isI = (u < 32);
      int kidx = isI ? u : u - 32;
#pragma unroll
      for (int bt = 0; bt < 2; ++bt)
#pragma unroll
        for (int rr = 0; rr < 4; ++rr) {
          int b = (2 * w + bt) * 16 + lk * 4 + rr;
          float s4[4], sum = 0.f;
#pragma unroll
          for (int ht = 0; ht < 4; ++ht) {
            float z = acc[un][bt][ht][rr] + bu[un][ht];
            float sg = __builtin_amdgcn_rcpf(1.0f + __expf(-z));
            s4[ht] = sg;
            sum += sg;
          }
          float r4 = sum;
          r4 += __shfl_xor(r4, 1, 64);
          r4 += __shfl_xor(r4, 2, 64);
          r4 += __shfl_xor(r4, 4, 64);
          r4 += __shfl_xor(r4, 8, 64);
          float wr = isI ? xmtp[b * 32 + u] : cL[b][kidx];
          float sc = wr * __builtin_amdgcn_rcpf(fmaxf(r4, 1e-12f));
#pragma unroll
          for (int ht = 0; ht < 4; ++ht) contrib[bt][ht][rr] += s4[ht] * sc;
        }
    }

    // o gate (redundant per WG, bit-identical)
    float o_v[2][4][4];
#pragma unroll
    for (int bt = 0; bt < 2; ++bt)
#pragma unroll
      for (int ht = 0; ht < 4; ++ht)
#pragma unroll
        for (int rr = 0; rr < 4; ++rr) {
          float z = aco[bt][ht][rr] + boR[ht];
          o_v[bt][ht][rr] = __builtin_amdgcn_rcpf(1.0f + __expf(-z));
        }

    // ---- cross-WG accumulate ----
    float* accT = accg + (t % 3) * 8192;
#pragma unroll
    for (int bt = 0; bt < 2; ++bt)
#pragma unroll
      for (int ht = 0; ht < 4; ++ht)
#pragma unroll
        for (int rr = 0; rr < 4; ++rr) {
          int b = (2 * w + bt) * 16 + lk * 4 + rr, h = ht * 16 + lr;
          unsafeAtomicAdd(&accT[b * 64 + h], contrib[bt][ht][rr]);
        }
    if (j == 0) {
      float* ob = obuf + (t & 1) * 8192;
#pragma unroll
      for (int bt = 0; bt < 2; ++bt)
#pragma unroll
        for (int ht = 0; ht < 4; ++ht)
#pragma unroll
          for (int rr = 0; rr < 4; ++rr) {
            int b = (2 * w + bt) * 16 + lk * 4 + rr, h = ht * 16 + lr;
            ST_RLX(&ob[b * 64 + h], o_v[bt][ht][rr]);
          }
    }

    // prefetch next x while we wait
    if (t + 1 < TT) {
      const float4* x4 = (const float4*)(xm + (size_t)(t + 1) * 4096);
      const float4* a4 = (const float4*)(xa + (size_t)(t + 1) * 4096);
#pragma unroll
      for (int k = 0; k < 4; ++k) {
        int idx4 = w * 256 + k * 64 + l;
        xmr[k] = x4[idx4];
        xar[k] = a4[idx4];
      }
    }

    // ---- THE barrier ----
    __syncthreads();
    if (tid == 0) {
      __hip_atomic_fetch_add(&ctr[t], 1u, __ATOMIC_RELEASE, __HIP_MEMORY_SCOPE_AGENT);
      while (LD_RLX(&ctr[t]) < (unsigned)NWG) __builtin_amdgcn_s_sleep(2);
    }
    __syncthreads();
    __threadfence();

    // ---- post: redundant c_new, wave-private state update, output slice ----
    float ns = 0.f;
#pragma unroll
    for (int bt = 0; bt < 2; ++bt)
#pragma unroll
      for (int ht = 0; ht < 4; ++ht)
#pragma unroll
        for (int rr = 0; rr < 4; ++rr) {
          int b = (2 * w + bt) * 16 + lk * 4 + rr, h = ht * 16 + lr;
          float mn = LD_RLX(&accT[b * 64 + h]);
          float cn_ = (1.0f - o_v[bt][ht][rr]) * mn;
          cL[b][h] = cn_;
          ns += fabsf(cn_);
        }

    {  // output slice + zero future acc buffer
      int e = j * 171 + tid;
      if (tid < 171 && e < 8192) {
        float mn = LD_RLX(&accT[e]);
        float ov = LD_RLX(&obuf[(t & 1) * 8192 + e]);
        out[(size_t)t * 8192 + e] = ov * mn;
        out[(size_t)(TT + t) * 8192 + e] = (1.0f - ov) * mn;
        ST_RLX(&accg[((t + 2) % 3) * 8192 + e], 0.f);
      }
    }

    // scalar L1 norm (identical bits in every WG)
    ns += __shfl_xor(ns, 1, 64);
    ns += __shfl_xor(ns, 2, 64);
    ns += __shfl_xor(ns, 4, 64);
    ns += __shfl_xor(ns, 8, 64);
    ns += __shfl_xor(ns, 16, 64);
    ns += __shfl_xor(ns, 32, 64);
    if (l == 0) nred[w] = ns;
    __syncthreads();
    float nm = nred[0] + nred[1] + nred[2] + nred[3];
    inv = __builtin_amdgcn_rcpf(nm + 1e-5f);
  }
}

extern "C" void kernel_launch(void* const* d_in, const int* in_sizes, int n_in,
                              void* d_out, int out_size, void* d_ws, size_t ws_size,
                              hipStream_t stream) {
  (void)in_sizes; (void)n_in; (void)out_size; (void)ws_size;
  const float* xm = (const float*)d_in[0];
  const float* xa = (const float*)d_in[1];
  const float* Wi = (const float*)d_in[2];
  const float* bi = (const float*)d_in[3];
  const float* Wr = (const float*)d_in[4];
  const float* br = (const float*)d_in[5];
  const float* Wo = (const float*)d_in[6];
  const float* bo = (const float*)d_in[7];

  char* ws = (char*)d_ws;
  f16* Wh        = (f16*)(ws + OFF_WH);
  float* accg    = (float*)(ws + OFF_ACC);
  float* obuf    = (float*)(ws + OFF_OB);
  unsigned* ctrp = (unsigned*)(ws + OFF_CTR);

  hipMemsetAsync(ws + ZERO_OFF, 0, ZERO_LEN, stream);
  prep_kernel<<<(97 * 8192 + 255) / 256, 256, 0, stream>>>(Wi, Wr, Wo, Wh);
  mclstm_kernel<<<NWG, 256, 0, stream>>>(xm, xa, bi, br, bo, Wh, accg, obuf, ctrp,
                                         (float*)d_out);
}